// Round 3
// baseline (233.961 us; speedup 1.0000x reference)
//
#include <hip/hip_runtime.h>
#include <stdint.h>

#define Bq 4
#define Sq 4096
#define DIN 512
#define Uq 128
#define Mq (Bq * Sq)

typedef __attribute__((ext_vector_type(8))) _Float16 f16x8;
typedef __attribute__((ext_vector_type(4))) float f32x4;
typedef unsigned short u16;

__device__ __forceinline__ u16 f2h(float f) {
  union { _Float16 h; u16 u; } v;
  v.h = (_Float16)f;
  return v.u;
}

// ---------------- W transpose: W[512][128] f32 -> Wt[128][512] fp16 ----------------
__global__ __launch_bounds__(256) void wt_kernel(const float* __restrict__ Wqp,
                                                 const float* __restrict__ Wkp,
                                                 const float* __restrict__ Wvp,
                                                 u16* __restrict__ wt) {
  int idx = blockIdx.x * 256 + threadIdx.x;   // 0 .. 3*65536-1
  int z = idx >> 16, r = idx & 65535;
  int n = r >> 9, k = r & 511;
  const float* W = (z == 0) ? Wqp : ((z == 1) ? Wkp : Wvp);
  wt[idx] = f2h(W[k * Uq + n]);
}

// ------------- fused QKV projection + ReLU -> fp16 (q,k row-major; v transposed) -------
// One block per 64-row tile computes ALL THREE projections: X read once.
__global__ __launch_bounds__(256) void proj_kernel(const float* __restrict__ X,
                                                   const u16* __restrict__ Wt,
                                                   const float* __restrict__ bqp,
                                                   const float* __restrict__ bkp,
                                                   const float* __restrict__ bvp,
                                                   u16* __restrict__ qkv) {
  const int mbase = blockIdx.x * 64;
  const int tid = threadIdx.x;
  const int wid = tid >> 6, lane = tid & 63;
  const int lo = lane & 15, g = lane >> 4;

  __shared__ __align__(16) u16 xt[64][40];   // 64 rows x 32 fp16 (+pad)

  f32x4 acc[3][8];
#pragma unroll
  for (int z = 0; z < 3; ++z)
#pragma unroll
    for (int f = 0; f < 8; ++f) acc[z][f] = (f32x4){0.f, 0.f, 0.f, 0.f};

  const int row = tid >> 2, cc = (tid & 3) * 8;
  const float* xsrc = X + (size_t)(mbase + row) * DIN + cc;
  float4 nv0 = *(const float4*)xsrc;
  float4 nv1 = *(const float4*)(xsrc + 4);
  const u16* wbase = Wt + (size_t)lo * 512 + 8 * g;

  for (int step = 0; step < 16; ++step) {
    {   // write staged tile (prev compute finished at loop-end barrier)
      union { u16 u[8]; uint4 v; } pk;
      pk.u[0] = f2h(nv0.x); pk.u[1] = f2h(nv0.y); pk.u[2] = f2h(nv0.z); pk.u[3] = f2h(nv0.w);
      pk.u[4] = f2h(nv1.x); pk.u[5] = f2h(nv1.y); pk.u[6] = f2h(nv1.z); pk.u[7] = f2h(nv1.w);
      *(uint4*)(&xt[row][cc]) = pk.v;
    }
    __syncthreads();
    if (step < 15) {   // prefetch next X tile into regs (hides under MFMA below)
      const float* s2 = xsrc + (step + 1) * 32;
      nv0 = *(const float4*)s2;
      nv1 = *(const float4*)(s2 + 4);
    }
    f16x8 a = *(const f16x8*)(&xt[16 * wid + lo][8 * g]);
#pragma unroll
    for (int z = 0; z < 3; ++z)
#pragma unroll
      for (int f = 0; f < 8; ++f) {
        f16x8 bfr = *(const f16x8*)(wbase + z * 65536 + f * 8192 + step * 32);
        acc[z][f] = __builtin_amdgcn_mfma_f32_16x16x32_f16(a, bfr, acc[z][f], 0, 0, 0);
      }
    __syncthreads();
  }

  // C/D layout: col = lane&15 (n), row = 4*(lane>>4)+reg (m)
#pragma unroll
  for (int z = 0; z < 3; ++z) {
    const float* bias = (z == 0) ? bqp : ((z == 1) ? bkp : bvp);
    if (z < 2) {
      u16* dst = qkv + (size_t)z * Mq * Uq;
#pragma unroll
      for (int f = 0; f < 8; ++f) {
        const int n = 16 * f + lo;
        const float bb = bias[n];
#pragma unroll
        for (int r = 0; r < 4; ++r) {
          const int m = mbase + 16 * wid + 4 * g + r;
          dst[(size_t)m * Uq + n] = f2h(fmaxf(acc[z][f][r] + bb, 0.f));
        }
      }
    } else {
      // v stored transposed: vT[batch][n][s]
      u16* vT = qkv + (size_t)2 * Mq * Uq;
      const int m0 = mbase + 16 * wid + 4 * g;
      const int bb_ = m0 >> 12, s0 = m0 & (Sq - 1);
#pragma unroll
      for (int f = 0; f < 8; ++f) {
        const int n = 16 * f + lo;
        const float bb = bias[n];
        ushort4 pv = make_ushort4(f2h(fmaxf(acc[z][f][0] + bb, 0.f)),
                                  f2h(fmaxf(acc[z][f][1] + bb, 0.f)),
                                  f2h(fmaxf(acc[z][f][2] + bb, 0.f)),
                                  f2h(fmaxf(acc[z][f][3] + bb, 0.f)));
        *(ushort4*)(vT + (size_t)bb_ * Uq * Sq + (size_t)n * Sq + s0) = pv;
      }
    }
  }
}

// ---------------- flash attention partials: per (split, 64-q-row tile) ----------------
// 256 threads = 4 waves, 16 q-rows/wave; kv range = kvlen per block.
__global__ __launch_bounds__(256, 3) void attn_kernel(const u16* __restrict__ qkv,
                                                      float* __restrict__ op,
                                                      float2* __restrict__ mlp,
                                                      int kvlen) {
  const int nb = gridDim.x;                 // 256 * nsplit
  const int bid = blockIdx.x;
  const int xcd = bid & 7, idx = bid >> 3;  // XCD-affine: batch b on XCDs {2b, 2b+1}
  const int b = xcd >> 1;
  const int within = (xcd & 1) * (nb >> 3) + idx;   // [0, 64*nsplit)
  const int split = within >> 6, qblk = within & 63;
  const int kv0 = split * kvlen;
  const int nit = kvlen >> 6;

  const int tid = threadIdx.x;
  const int wid = tid >> 6, lane = tid & 63;
  const int lo = lane & 15, g = lane >> 4;

  const u16* kbase = qkv + (size_t)Mq * Uq + (size_t)b * Sq * Uq;
  const u16* vbase = qkv + (size_t)2 * Mq * Uq + (size_t)b * Uq * Sq;

  __shared__ __align__(16) unsigned char kt[64 * 256];        // K tile, XOR-swizzled
  __shared__ __align__(16) unsigned char vt[128 * 144];       // vT tile, padded rows
  __shared__ __align__(16) unsigned char plds[4][16 * 144];   // per-wave P round-trip

  // staging addresses (4 x 16B chunks per thread for each of K, V)
  const u16* ka[4]; int koff[4];
  const u16* va[4]; int voff[4];
#pragma unroll
  for (int i = 0; i < 4; ++i) {
    const int c = tid + 256 * i;
    const int r = c >> 4, gg = c & 15;
    ka[i] = kbase + (size_t)(kv0 + r) * Uq + gg * 8;
    koff[i] = r * 256 + ((gg ^ (r & 7)) << 4);
    const int n = c >> 3, g2 = c & 7;
    va[i] = vbase + (size_t)n * Sq + kv0 + g2 * 8;
    voff[i] = n * 144 + g2 * 16;
  }
  uint4 kreg[4], vreg[4];
#pragma unroll
  for (int i = 0; i < 4; ++i) { kreg[i] = *(const uint4*)ka[i]; vreg[i] = *(const uint4*)va[i]; }

  // Q frags (B operand of swapped QK^T), held in regs
  const int qrow = b * Sq + qblk * 64 + wid * 16 + lo;
  f16x8 qf[4];
#pragma unroll
  for (int t = 0; t < 4; ++t)
    qf[t] = *(const f16x8*)(qkv + (size_t)qrow * Uq + 32 * t + 8 * g);

  f32x4 acc[8];
#pragma unroll
  for (int f = 0; f < 8; ++f) acc[f] = (f32x4){0.f, 0.f, 0.f, 0.f};
  float m_run = -1e30f, l_run = 0.f;

  for (int it = 0; it < nit; ++it) {
    __syncthreads();          // prev compute done -> LDS free
#pragma unroll
    for (int i = 0; i < 4; ++i) {
      *(uint4*)(&kt[koff[i]]) = kreg[i];
      *(uint4*)(&vt[voff[i]]) = vreg[i];
    }
    __syncthreads();
    if (it + 1 < nit) {       // async-stage: issue next-tile loads, consumed next iter
#pragma unroll
      for (int i = 0; i < 4; ++i) {
        ka[i] += 64 * Uq; va[i] += 64;
        kreg[i] = *(const uint4*)ka[i];
        vreg[i] = *(const uint4*)va[i];
      }
    }

    // ---- QK^T (swapped): lane owns q = lo, kv = 16h + 4g + r ----
    f32x4 sf[4];
    __builtin_amdgcn_s_setprio(1);
#pragma unroll
    for (int h = 0; h < 4; ++h) {
      sf[h] = (f32x4){0.f, 0.f, 0.f, 0.f};
      const int row = 16 * h + lo;
#pragma unroll
      for (int t = 0; t < 4; ++t) {
        f16x8 a = *(const f16x8*)(&kt[row * 256 + ((64 * t + 16 * g) ^ ((lo & 7) << 4))]);
        sf[h] = __builtin_amdgcn_mfma_f32_16x16x32_f16(a, qf[t], sf[h], 0, 0, 0);
      }
    }
    __builtin_amdgcn_s_setprio(0);

    // ---- online softmax (row q = lo, values spread over g) ----
    float tmax = -1e30f;
#pragma unroll
    for (int h = 0; h < 4; ++h)
#pragma unroll
      for (int r = 0; r < 4; ++r) tmax = fmaxf(tmax, sf[h][r]);
    tmax = fmaxf(tmax, __shfl_xor(tmax, 16));
    tmax = fmaxf(tmax, __shfl_xor(tmax, 32));

    if (__any(tmax > m_run)) {
      const float m_new = fmaxf(m_run, tmax);
      const float scale = __expf(m_run - m_new);
#pragma unroll
      for (int r = 0; r < 4; ++r) {
        const float sc = __shfl(scale, 4 * g + r);   // acc rows are q = 4g+r
#pragma unroll
        for (int f = 0; f < 8; ++f) acc[f][r] *= sc;
      }
      l_run *= scale;
      m_run = m_new;
    }

    float psum = 0.f;
    u16 pb[16];
#pragma unroll
    for (int h = 0; h < 4; ++h)
#pragma unroll
      for (int r = 0; r < 4; ++r) {
        const float pv = __expf(sf[h][r] - m_run);
        psum += pv;
        pb[4 * h + r] = f2h(pv);
      }
    psum += __shfl_xor(psum, 16);
    psum += __shfl_xor(psum, 32);
    l_run += psum;

    // ---- P re-fragment through per-wave LDS (row lo = linear kv*2 bytes) ----
#pragma unroll
    for (int h = 0; h < 4; ++h) {
      ushort4 p4 = make_ushort4(pb[4 * h + 0], pb[4 * h + 1], pb[4 * h + 2], pb[4 * h + 3]);
      *(ushort4*)(&plds[wid][lo * 144 + 32 * h + 8 * g]) = p4;
    }

    // ---- PV: acc[q=4g+r][n] += P[q][kv] * V[kv][n] ----
    __builtin_amdgcn_s_setprio(1);
#pragma unroll
    for (int s = 0; s < 2; ++s) {
      f16x8 pa = *(const f16x8*)(&plds[wid][lo * 144 + 64 * s + 16 * g]);
#pragma unroll
      for (int f = 0; f < 8; ++f) {
        f16x8 bv = *(const f16x8*)(&vt[(16 * f + lo) * 144 + 64 * s + 16 * g]);
        acc[f] = __builtin_amdgcn_mfma_f32_16x16x32_f16(pa, bv, acc[f], 0, 0, 0);
      }
    }
    __builtin_amdgcn_s_setprio(0);
  }

  // ---- write unnormalized partials + (m,l) ----
  const size_t rb = (size_t)split * Mq + (size_t)b * Sq + qblk * 64 + wid * 16;
  if (g == 0) mlp[rb + lo] = make_float2(m_run, l_run);
  float* od = op + rb * Uq;
#pragma unroll
  for (int f = 0; f < 8; ++f) {
    const int n = 16 * f + lo;
#pragma unroll
    for (int r = 0; r < 4; ++r)
      od[(size_t)(4 * g + r) * Uq + n] = acc[f][r];
  }
}

// ---------------- combine kv-split partials ----------------
__global__ __launch_bounds__(256) void combine_kernel(const float* __restrict__ op,
                                                      const float2* __restrict__ mlp,
                                                      float* __restrict__ out,
                                                      int nsplit) {
  const int idx = blockIdx.x * 256 + threadIdx.x;   // Mq*32
  const int q = idx >> 5, nq = idx & 31;
  float M = -1e30f;
  for (int s = 0; s < nsplit; ++s) M = fmaxf(M, mlp[(size_t)s * Mq + q].x);
  float L = 0.f;
  float ox = 0.f, oy = 0.f, oz = 0.f, ow = 0.f;
  for (int s = 0; s < nsplit; ++s) {
    const float2 ml = mlp[(size_t)s * Mq + q];
    const float w = __expf(ml.x - M);
    L += w * ml.y;
    const float4 v = *(const float4*)(op + ((size_t)s * Mq + q) * Uq + nq * 4);
    ox += w * v.x; oy += w * v.y; oz += w * v.z; ow += w * v.w;
  }
  const float inv = 1.f / L;
  *(float4*)(out + (size_t)q * Uq + nq * 4) = make_float4(ox * inv, oy * inv, oz * inv, ow * inv);
}

extern "C" void kernel_launch(void* const* d_in, const int* in_sizes, int n_in,
                              void* d_out, int out_size, void* d_ws, size_t ws_size,
                              hipStream_t stream) {
  const float* X   = (const float*)d_in[0];
  const float* Wqp = (const float*)d_in[1];
  const float* bqp = (const float*)d_in[2];
  const float* Wkp = (const float*)d_in[3];
  const float* bkp = (const float*)d_in[4];
  const float* Wvp = (const float*)d_in[5];
  const float* bvp = (const float*)d_in[6];
  float* out = (float*)d_out;

  u16* qkv = (u16*)d_ws;                                   // q(4MB) k(4MB) vT(4MB) fp16
  u16* wt  = qkv + (size_t)3 * Mq * Uq;                    // 3 x [128][512] fp16
  float* op = (float*)(wt + 3 * 65536);                    // partial O, nsplit x Mq x Uq f32

  const size_t base = (size_t)12976128;                    // qkv + wt bytes
  const size_t per  = (size_t)8519680;                     // per-split op+ml bytes
  int nsplit = 4;
  if (ws_size < base + 4 * per) nsplit = 2;
  if (ws_size < base + 2 * per) nsplit = 1;
  float2* mlp = (float2*)(op + (size_t)nsplit * Mq * Uq);

  wt_kernel<<<768, 256, 0, stream>>>(Wqp, Wkp, Wvp, wt);
  proj_kernel<<<Mq / 64, 256, 0, stream>>>(X, wt, bqp, bkp, bvp, qkv);
  attn_kernel<<<256 * nsplit, 256, 0, stream>>>(qkv, op, mlp, Sq / nsplit);
  combine_kernel<<<(Mq * 32) / 256, 256, 0, stream>>>(op, mlp, out, nsplit);
}

// Round 4
// 141.228 us; speedup vs baseline: 1.6566x; 1.6566x over previous
//
#include <hip/hip_runtime.h>
#include <stdint.h>

#define Bq 4
#define Sq 4096
#define DIN 512
#define Uq 128
#define Mq (Bq * Sq)

typedef __attribute__((ext_vector_type(8))) _Float16 f16x8;
typedef __attribute__((ext_vector_type(4))) float f32x4;
typedef unsigned short u16;

__device__ __forceinline__ u16 f2h(float f) {
  union { _Float16 h; u16 u; } v;
  v.h = (_Float16)f;
  return v.u;
}

// async global -> LDS, 16B per lane. LDS dest = uniform base + lane*16 (linear).
__device__ __forceinline__ void gl_lds16(const void* g, void* l) {
  __builtin_amdgcn_global_load_lds(
      (const __attribute__((address_space(1))) unsigned int*)g,
      (__attribute__((address_space(3))) unsigned int*)l, 16, 0, 0);
}

// ---------------- W transpose: W[512][128] f32 -> Wt[128][512] fp16 ----------------
__global__ __launch_bounds__(256) void wt_kernel(const float* __restrict__ Wqp,
                                                 const float* __restrict__ Wkp,
                                                 const float* __restrict__ Wvp,
                                                 u16* __restrict__ wt) {
  int idx = blockIdx.x * 256 + threadIdx.x;   // 0 .. 3*65536-1
  int z = idx >> 16, r = idx & 65535;
  int n = r >> 9, k = r & 511;
  const float* W = (z == 0) ? Wqp : ((z == 1) ? Wkp : Wvp);
  wt[idx] = f2h(W[k * Uq + n]);
}

// ------------- fused QKV projection + ReLU -> fp16 (q,k row-major; v transposed) -------
// 32-row tiles, 128 threads (2 waves), grid 512 -> 2 blocks/CU. X read once.
__global__ __launch_bounds__(128) void proj_kernel(const float* __restrict__ X,
                                                   const u16* __restrict__ Wt,
                                                   const float* __restrict__ bqp,
                                                   const float* __restrict__ bkp,
                                                   const float* __restrict__ bvp,
                                                   u16* __restrict__ qkv) {
  const int mbase = blockIdx.x * 32;
  const int tid = threadIdx.x;
  const int wid = tid >> 6, lane = tid & 63;
  const int lo = lane & 15, g = lane >> 4;

  __shared__ __align__(16) u16 xt[32][40];   // 32 rows x 32 fp16 (+pad)

  f32x4 acc[3][8];
#pragma unroll
  for (int z = 0; z < 3; ++z)
#pragma unroll
    for (int f = 0; f < 8; ++f) acc[z][f] = (f32x4){0.f, 0.f, 0.f, 0.f};

  const int row = tid >> 2, cc = (tid & 3) * 8;
  const float* xsrc = X + (size_t)(mbase + row) * DIN + cc;
  float4 nv0 = *(const float4*)xsrc;
  float4 nv1 = *(const float4*)(xsrc + 4);
  const u16* wbase = Wt + (size_t)lo * 512 + 8 * g;

  for (int step = 0; step < 16; ++step) {
    {   // write staged tile
      union { u16 u[8]; uint4 v; } pk;
      pk.u[0] = f2h(nv0.x); pk.u[1] = f2h(nv0.y); pk.u[2] = f2h(nv0.z); pk.u[3] = f2h(nv0.w);
      pk.u[4] = f2h(nv1.x); pk.u[5] = f2h(nv1.y); pk.u[6] = f2h(nv1.z); pk.u[7] = f2h(nv1.w);
      *(uint4*)(&xt[row][cc]) = pk.v;
    }
    __syncthreads();
    if (step < 15) {   // prefetch next X tile into regs
      const float* s2 = xsrc + (step + 1) * 32;
      nv0 = *(const float4*)s2;
      nv1 = *(const float4*)(s2 + 4);
    }
    f16x8 a = *(const f16x8*)(&xt[16 * wid + lo][8 * g]);
#pragma unroll
    for (int z = 0; z < 3; ++z)
#pragma unroll
      for (int f = 0; f < 8; ++f) {
        f16x8 bfr = *(const f16x8*)(wbase + z * 65536 + f * 8192 + step * 32);
        acc[z][f] = __builtin_amdgcn_mfma_f32_16x16x32_f16(a, bfr, acc[z][f], 0, 0, 0);
      }
    __syncthreads();
  }

  // C/D layout: col = lane&15 (n), row = 4*(lane>>4)+reg (m)
#pragma unroll
  for (int z = 0; z < 3; ++z) {
    const float* bias = (z == 0) ? bqp : ((z == 1) ? bkp : bvp);
    if (z < 2) {
      u16* dst = qkv + (size_t)z * Mq * Uq;
#pragma unroll
      for (int f = 0; f < 8; ++f) {
        const int n = 16 * f + lo;
        const float bb = bias[n];
#pragma unroll
        for (int r = 0; r < 4; ++r) {
          const int m = mbase + 16 * wid + 4 * g + r;
          dst[(size_t)m * Uq + n] = f2h(fmaxf(acc[z][f][r] + bb, 0.f));
        }
      }
    } else {
      u16* vT = qkv + (size_t)2 * Mq * Uq;   // vT[batch][n][s]
      const int m0 = mbase + 16 * wid + 4 * g;
      const int bb_ = m0 >> 12, s0 = m0 & (Sq - 1);
#pragma unroll
      for (int f = 0; f < 8; ++f) {
        const int n = 16 * f + lo;
        const float bb = bias[n];
        ushort4 pv = make_ushort4(f2h(fmaxf(acc[z][f][0] + bb, 0.f)),
                                  f2h(fmaxf(acc[z][f][1] + bb, 0.f)),
                                  f2h(fmaxf(acc[z][f][2] + bb, 0.f)),
                                  f2h(fmaxf(acc[z][f][3] + bb, 0.f)));
        *(ushort4*)(vT + (size_t)bb_ * Uq * Sq + (size_t)n * Sq + s0) = pv;
      }
    }
  }
}

// ---------------- flash attention partials ----------------
// 256 threads = 4 waves, 16 q-rows/wave, 64 q-rows/block; KBLK=64 per iter.
// K/V staged via global_load_lds (double-buffered), swizzle pre-applied on the
// GLOBAL source address: LDS[r][c] = G[r][c ^ (r&7)] (16B chunks).
__global__ __launch_bounds__(256) void attn_kernel(const u16* __restrict__ qkv,
                                                   float* __restrict__ op,
                                                   float2* __restrict__ mlp,
                                                   int kvlen) {
  const int nb = gridDim.x;
  const int bid = blockIdx.x;
  const int xcd = bid & 7, idx = bid >> 3;  // hw XCD = bid % 8
  const int b = xcd >> 1;                    // batch pinned to 2 XCDs
  const int within = (xcd & 1) * (nb >> 3) + idx;
  const int split = within >> 6, qblk = within & 63;
  const int kv0 = split * kvlen;
  const int nit = kvlen >> 6;

  const int tid = threadIdx.x;
  const int wid = tid >> 6, lane = tid & 63;
  const int lo = lane & 15, g = lane >> 4;

  const u16* kbase = qkv + (size_t)Mq * Uq + (size_t)b * Sq * Uq;
  const u16* vbase = qkv + (size_t)2 * Mq * Uq + (size_t)b * Uq * Sq;

  __shared__ __align__(16) unsigned char kt[2][16384];   // 64 rows x 256B
  __shared__ __align__(16) unsigned char vt[2][16384];   // 128 rows x 128B
  __shared__ __align__(16) unsigned char plds[4][2304];  // per-wave P round-trip

  // per-lane pre-swizzled global offsets.
  // K: region = 4 rows x 16 chunks; lane -> (row s4, chunk j16); load G[r][j^(r&7)]
  const int s4 = lane >> 4, j16 = lane & 15;
  const int ko = s4 * 256 + ((j16 ^ s4) << 4);
  // V: region = 8 rows x 8 chunks; lane -> (row s8, chunk j8)
  const int s8 = lane >> 3, j8 = lane & 7;
  const int vo = s8 * 8192 + ((j8 ^ s8) << 4);

  const char* kgp0 = (const char*)kbase + (size_t)kv0 * 256 + wid * 4096 + ko;
  const char* kgp1 = (const char*)kbase + (size_t)kv0 * 256 + wid * 4096 + (ko ^ 64);
  const char* vgp  = (const char*)vbase + (size_t)kv0 * 2 + (size_t)wid * 262144 + vo;

#define STAGE(bufi) do {                                      \
    char* kl = (char*)&kt[bufi][wid * 4096];                  \
    char* vl = (char*)&vt[bufi][wid * 4096];                  \
    gl_lds16(kgp0,           kl);                             \
    gl_lds16(kgp1 + 1024,    kl + 1024);                      \
    gl_lds16(kgp0 + 2048,    kl + 2048);                      \
    gl_lds16(kgp1 + 3072,    kl + 3072);                      \
    gl_lds16(vgp,            vl);                             \
    gl_lds16(vgp + 65536,    vl + 1024);                      \
    gl_lds16(vgp + 131072,   vl + 2048);                      \
    gl_lds16(vgp + 196608,   vl + 3072);                      \
  } while (0)

  // Q frags (B operand of swapped QK^T), held in regs
  const int qrow = b * Sq + qblk * 64 + wid * 16 + lo;
  f16x8 qf[4];
#pragma unroll
  for (int t = 0; t < 4; ++t)
    qf[t] = *(const f16x8*)(qkv + (size_t)qrow * Uq + 32 * t + 8 * g);

  f32x4 acc[8];
#pragma unroll
  for (int f = 0; f < 8; ++f) acc[f] = (f32x4){0.f, 0.f, 0.f, 0.f};
  float m_run = -1e30f, l_run = 0.f;

  STAGE(0);   // prologue: tile 0 in flight

  for (int it = 0; it < nit; ++it) {
    if (it + 1 < nit) {
      kgp0 += 16384; kgp1 += 16384; vgp += 128;
      STAGE((it + 1) & 1);                                   // tile it+1 in flight
      asm volatile("s_waitcnt vmcnt(8)" ::: "memory");       // tile it landed
    } else {
      asm volatile("s_waitcnt vmcnt(0)" ::: "memory");
    }
    __builtin_amdgcn_sched_barrier(0);
    __builtin_amdgcn_s_barrier();          // raw barrier: no vmcnt(0) drain
    __builtin_amdgcn_sched_barrier(0);

    const unsigned char* ktc = kt[it & 1];
    const unsigned char* vtc = vt[it & 1];

    // ---- QK^T (swapped): lane owns q = lo, kv = 16h + 4g + r ----
    f32x4 sf[4];
    __builtin_amdgcn_s_setprio(1);
#pragma unroll
    for (int h = 0; h < 4; ++h) {
      sf[h] = (f32x4){0.f, 0.f, 0.f, 0.f};
      const int row = 16 * h + lo;
#pragma unroll
      for (int t = 0; t < 4; ++t) {
        f16x8 a = *(const f16x8*)(&ktc[row * 256 + ((64 * t + 16 * g) ^ ((lo & 7) << 4))]);
        sf[h] = __builtin_amdgcn_mfma_f32_16x16x32_f16(a, qf[t], sf[h], 0, 0, 0);
      }
    }
    __builtin_amdgcn_s_setprio(0);

    // ---- online softmax (row q = lo, values spread over g) ----
    float tmax = -1e30f;
#pragma unroll
    for (int h = 0; h < 4; ++h)
#pragma unroll
      for (int r = 0; r < 4; ++r) tmax = fmaxf(tmax, sf[h][r]);
    tmax = fmaxf(tmax, __shfl_xor(tmax, 16));
    tmax = fmaxf(tmax, __shfl_xor(tmax, 32));

    if (__any(tmax > m_run)) {
      const float m_new = fmaxf(m_run, tmax);
      const float scale = __expf(m_run - m_new);
#pragma unroll
      for (int r = 0; r < 4; ++r) {
        const float sc = __shfl(scale, 4 * g + r);   // acc rows are q = 4g+r
#pragma unroll
        for (int f = 0; f < 8; ++f) acc[f][r] *= sc;
      }
      l_run *= scale;
      m_run = m_new;
    }

    float psum = 0.f;
    u16 pb[16];
#pragma unroll
    for (int h = 0; h < 4; ++h)
#pragma unroll
      for (int r = 0; r < 4; ++r) {
        const float pv = __expf(sf[h][r] - m_run);
        psum += pv;
        pb[4 * h + r] = f2h(pv);
      }
    psum += __shfl_xor(psum, 16);
    psum += __shfl_xor(psum, 32);
    l_run += psum;

    // ---- P re-fragment through per-wave LDS ----
#pragma unroll
    for (int h = 0; h < 4; ++h) {
      ushort4 p4 = make_ushort4(pb[4 * h + 0], pb[4 * h + 1], pb[4 * h + 2], pb[4 * h + 3]);
      *(ushort4*)(&plds[wid][lo * 144 + 32 * h + 8 * g]) = p4;
    }

    // ---- PV: acc[q=4g+r][n] += P[q][kv] * V[kv][n] ----
    __builtin_amdgcn_s_setprio(1);
#pragma unroll
    for (int s = 0; s < 2; ++s) {
      f16x8 pa = *(const f16x8*)(&plds[wid][lo * 144 + 64 * s + 16 * g]);
#pragma unroll
      for (int f = 0; f < 8; ++f) {
        const int n = 16 * f + lo;
        f16x8 bv = *(const f16x8*)(&vtc[n * 128 + ((64 * s + 16 * g) ^ ((lo & 7) << 4))]);
        acc[f] = __builtin_amdgcn_mfma_f32_16x16x32_f16(pa, bv, acc[f], 0, 0, 0);
      }
    }
    __builtin_amdgcn_s_setprio(0);

    __builtin_amdgcn_s_barrier();          // all reads of this buffer done
  }
#undef STAGE

  // ---- write unnormalized partials + (m,l) ----
  const size_t rb = (size_t)split * Mq + (size_t)b * Sq + qblk * 64 + wid * 16;
  if (g == 0) mlp[rb + lo] = make_float2(m_run, l_run);
  float* od = op + rb * Uq;
#pragma unroll
  for (int f = 0; f < 8; ++f) {
    const int n = 16 * f + lo;
#pragma unroll
    for (int r = 0; r < 4; ++r)
      od[(size_t)(4 * g + r) * Uq + n] = acc[f][r];
  }
}

// ---------------- combine kv-split partials ----------------
__global__ __launch_bounds__(256) void combine_kernel(const float* __restrict__ op,
                                                      const float2* __restrict__ mlp,
                                                      float* __restrict__ out,
                                                      int nsplit) {
  const int idx = blockIdx.x * 256 + threadIdx.x;   // Mq*32
  const int q = idx >> 5, nq = idx & 31;
  float M = -1e30f;
  for (int s = 0; s < nsplit; ++s) M = fmaxf(M, mlp[(size_t)s * Mq + q].x);
  float L = 0.f;
  float ox = 0.f, oy = 0.f, oz = 0.f, ow = 0.f;
  for (int s = 0; s < nsplit; ++s) {
    const float2 ml = mlp[(size_t)s * Mq + q];
    const float w = __expf(ml.x - M);
    L += w * ml.y;
    const float4 v = *(const float4*)(op + ((size_t)s * Mq + q) * Uq + nq * 4);
    ox += w * v.x; oy += w * v.y; oz += w * v.z; ow += w * v.w;
  }
  const float inv = 1.f / L;
  *(float4*)(out + (size_t)q * Uq + nq * 4) = make_float4(ox * inv, oy * inv, oz * inv, ow * inv);
}

extern "C" void kernel_launch(void* const* d_in, const int* in_sizes, int n_in,
                              void* d_out, int out_size, void* d_ws, size_t ws_size,
                              hipStream_t stream) {
  const float* X   = (const float*)d_in[0];
  const float* Wqp = (const float*)d_in[1];
  const float* bqp = (const float*)d_in[2];
  const float* Wkp = (const float*)d_in[3];
  const float* bkp = (const float*)d_in[4];
  const float* Wvp = (const float*)d_in[5];
  const float* bvp = (const float*)d_in[6];
  float* out = (float*)d_out;

  u16* qkv = (u16*)d_ws;                                   // q(4MB) k(4MB) vT(4MB) fp16
  u16* wt  = qkv + (size_t)3 * Mq * Uq;                    // 3 x [128][512] fp16
  float* op = (float*)(wt + 3 * 65536);                    // partial O

  const size_t base = (size_t)12976128;                    // qkv + wt bytes
  const size_t per  = (size_t)8519680;                     // per-split op+ml bytes
  int nsplit = 2;                                          // 512 blocks = 2/CU, 1 round
  if (ws_size < base + 2 * per) nsplit = 1;
  float2* mlp = (float2*)(op + (size_t)nsplit * Mq * Uq);

  wt_kernel<<<768, 256, 0, stream>>>(Wqp, Wkp, Wvp, wt);
  proj_kernel<<<Mq / 32, 128, 0, stream>>>(X, wt, bqp, bkp, bvp, qkv);
  attn_kernel<<<256 * nsplit, 256, 0, stream>>>(qkv, op, mlp, Sq / nsplit);
  combine_kernel<<<(Mq * 32) / 256, 256, 0, stream>>>(op, mlp, out, nsplit);
}